// Round 6
// baseline (801.253 us; speedup 1.0000x reference)
//
#include <hip/hip_runtime.h>
#include <cstdint>

#define S_   2048
#define H_   4096
#define NH_  32
#define NKV_ 8
#define HD_  128

typedef short  short8  __attribute__((ext_vector_type(8)));
typedef float  floatx4 __attribute__((ext_vector_type(4)));
typedef unsigned int uintx2 __attribute__((ext_vector_type(2)));
typedef unsigned int uint32;
typedef unsigned short ushort16;

__device__ inline unsigned int pk_bf16(float a, float b) {
  unsigned int ua = __builtin_bit_cast(unsigned int, a) + 0x8000u;
  unsigned int ub = __builtin_bit_cast(unsigned int, b) + 0x8000u;
  return __builtin_amdgcn_perm(ub, ua, 0x07060302u);
}
__device__ inline unsigned short f32_bf16(float a) {
  return (unsigned short)((__builtin_bit_cast(unsigned int, a) + 0x8000u) >> 16);
}
__device__ inline float exp2_fast(float x) {
  float r; asm("v_exp_f32 %0, %1" : "=v"(r) : "v"(x)); return r;
}

__device__ inline void gld16(const ushort16* g, ushort16* l) {
  __builtin_amdgcn_global_load_lds((const __attribute__((address_space(1))) void*)g,
                                   (__attribute__((address_space(3))) void*)l, 16, 0, 0);
}

// fp32 -> bf16 elementwise, 4 elems/thread. grid = n/1024.
__global__ __launch_bounds__(256)
void cvt_bf16(const float* __restrict__ in, uint32* __restrict__ out) {
  const int idx = blockIdx.x * 256 + threadIdx.x;
  floatx4 v = ((const floatx4*)in)[idx];
  uintx2 o;
  o[0] = pk_bf16(v[0], v[1]);
  o[1] = pk_bf16(v[2], v[3]);
  ((uintx2*)out)[idx] = o;
}

// bf16 transpose: in [4096 x 1024] -> out [1024 x 4096]. grid (16, 64), 256 thr.
__global__ __launch_bounds__(256)
void transp(const ushort16* __restrict__ in, ushort16* __restrict__ out) {
  __shared__ __align__(16) ushort16 T[64 * 66];
  const int tid = threadIdx.x, wave = tid >> 6, j = tid & 63;
  const int c0 = blockIdx.x * 64, r0 = blockIdx.y * 64;
#pragma unroll
  for (int it = 0; it < 16; it++) {
    const int i = it * 4 + wave;
    T[i * 66 + j] = in[(size_t)(r0 + i) * 1024 + c0 + j];
  }
  __syncthreads();
#pragma unroll
  for (int it = 0; it < 16; it++) {
    const int i = it * 4 + wave;
    out[(size_t)(c0 + i) * 4096 + r0 + j] = T[j * 66 + i];
  }
}

// Y(M x N) = A(M x 4096) @ B(N x 4096)^T, all bf16 in, m97-style 128x128 tile.
// Kept for the N=1024 GEMMs (K/V proj): grid (8,32) = 256 wg (full CU fill).
template<bool ROPE, bool SCALE, bool OUTF32>
__global__ __launch_bounds__(256)
void gemm128(const ushort16* __restrict__ A, const ushort16* __restrict__ B,
             void* __restrict__ Y, int N,
             const float* __restrict__ cosT, const float* __restrict__ sinT)
{
  constexpr int K = H_;
  __shared__ __align__(16) ushort16 As[128 * 32];
  __shared__ __align__(16) ushort16 Bs[128 * 32];
  const int bn = blockIdx.x * 128, bm = blockIdx.y * 128;
  const int tid = threadIdx.x, wave = tid >> 6, lane = tid & 63;
  const int l15 = lane & 15, quad = lane >> 4;
  const int wr = (wave & 1) * 64, wc = (wave >> 1) * 64;

  const int crow = lane >> 2;
  const int ckb  = (lane & 3) ^ ((lane >> 3) & 3);
  const int q0 = wave * 2, q1 = q0 + 1;
  const ushort16* gA0 = A + (size_t)(bm + q0 * 16 + crow) * K + ckb * 8;
  const ushort16* gA1 = A + (size_t)(bm + q1 * 16 + crow) * K + ckb * 8;
  const ushort16* gB0 = B + (size_t)(bn + q0 * 16 + crow) * K + ckb * 8;
  const ushort16* gB1 = B + (size_t)(bn + q1 * 16 + crow) * K + ckb * 8;
  ushort16* lA0 = As + q0 * 512;
  ushort16* lA1 = As + q1 * 512;
  ushort16* lB0 = Bs + q0 * 512;
  ushort16* lB1 = Bs + q1 * 512;

  const int slot = quad ^ ((l15 >> 1) & 3);
  int aoff[4], boff[4];
#pragma unroll
  for (int t = 0; t < 4; t++) {
    aoff[t] = (wr + t * 16 + l15) * 32 + slot * 8;
    boff[t] = (wc + t * 16 + l15) * 32 + slot * 8;
  }

  floatx4 acc[4][4] = {};

  for (int k0 = 0; k0 < K; k0 += 32) {
    __syncthreads();
    gld16(gA0 + k0, lA0);
    gld16(gA1 + k0, lA1);
    gld16(gB0 + k0, lB0);
    gld16(gB1 + k0, lB1);
    __syncthreads();

    short8 af[4], bf[4];
#pragma unroll
    for (int t = 0; t < 4; t++) af[t] = *(const short8*)(As + aoff[t]);
#pragma unroll
    for (int t = 0; t < 4; t++) bf[t] = *(const short8*)(Bs + boff[t]);
#pragma unroll
    for (int mt = 0; mt < 4; mt++)
#pragma unroll
      for (int nt = 0; nt < 4; nt++)
        acc[mt][nt] = __builtin_amdgcn_mfma_f32_16x16x32_bf16(af[mt], bf[nt], acc[mt][nt], 0, 0, 0);
  }

#pragma unroll
  for (int mt = 0; mt < 4; mt++) {
#pragma unroll
    for (int nt = 0; nt < 4; nt++) {
      const int col = bn + wc + nt * 16 + l15;
#pragma unroll
      for (int r = 0; r < 4; r++) {
        const int row = bm + wr + mt * 16 + quad * 4 + r;
        float v = acc[mt][nt][r];
        if (ROPE) {
          float other = __shfl_xor(v, 1, 64);
          const int pos = row & (S_ - 1);
          const int i   = (col & (HD_ - 1)) >> 1;
          const float c  = cosT[pos * (HD_ / 2) + i];
          const float sn = sinT[pos * (HD_ / 2) + i];
          v = (lane & 1) ? (other * sn + v * c) : (v * c - other * sn);
        }
        // 1/sqrt(128) * log2(e): softmax runs in exp2 domain downstream
        if (SCALE) v *= (0.08838834764831845f * 1.4426950408889634f);
        if (OUTF32) ((float*)Y)[(size_t)row * N + col] = v;
        else        ((ushort16*)Y)[(size_t)row * N + col] = f32_bf16(v);
      }
    }
  }
}

// 256x256-tile 8-phase/2-K-tile GEMM (m201-faithful T2+T3+T4+T5), N=4096 GEMMs.
// v2 vs v1: reads balanced 8,4,8,4 per phase (was 12,4,8,0) via a register
// double-buffer for the B(n0-1) fragments: phase 4 of tile t reads tile t+1's
// B(n0-1) into the OTHER reg bank while its MFMA consumes the old bank
// (static reg indexing -> loop unrolled over tile parity, rule #20).
// Uniform s_waitcnt vmcnt(6) at EVERY phase end: queue at each phase end is
// exactly 4 half-tiles = 8 loads; vmcnt(6) confirms precisely the half-tile
// the next phase reads (3-half-tile lead, never drained until the last 2 tiles).
// Staging map (tile t): P1->A0(t+1), P2->B1(t+1), P3->A1(t+1), P4->B0(t+2);
// every LDS overwrite lands >=4 phases after that region's last read.
template<bool ROPE, bool SCALE, bool OUTF32>
__global__ __launch_bounds__(512, 2)
void gemm256(const ushort16* __restrict__ A, const ushort16* __restrict__ B,
             void* __restrict__ Y, int N,
             const float* __restrict__ cosT, const float* __restrict__ sinT)
{
  constexpr int NT = H_ / 64;                      // 64 K-tiles
  __shared__ __align__(16) ushort16 LA[2][16384];  // [buf][256 rows x 64 k] bf16, 32KB
  __shared__ __align__(16) ushort16 LB[2][16384];

  // XCD-bijective swizzle (gridDim.x = 256, divisible by 8)
  const int bid = (int)blockIdx.x;
  const int wg  = (bid & 7) * ((int)gridDim.x >> 3) + (bid >> 3);
  const int nbx = N >> 8;
  const int bm = (wg / nbx) * 256, bn = (wg % nbx) * 256;

  const int tid = threadIdx.x, wave = tid >> 6, lane = tid & 63;
  const int l15 = lane & 15, quad = lane >> 4;
  const int wm = wave >> 2, wn = wave & 3;

  // staging: 1024 16B-chunks per half-tile, 2 per thread; XOR pre-swizzle on
  // the global source, linear LDS dest (rule #21).
  const int s1 = 512 + tid;
  const int off0 = (tid >> 3) * 4096 + (((tid & 7) ^ ((tid >> 3) & 7)) * 8);
  const int off1 = (s1  >> 3) * 4096 + (((s1  & 7) ^ ((s1  >> 3) & 7)) * 8);

  auto STG_A = [&](int kt, int h) {
    const ushort16* g = A + (size_t)(bm + h * 128) * 4096 + kt * 64;
    ushort16* d = &LA[kt & 1][h * 8192 + wave * 512];
    gld16(g + off0, d);
    gld16(g + off1, d + 4096);
  };
  auto STG_B = [&](int kt, int h) {
    const ushort16* g = B + (size_t)(bn + h * 128) * 4096 + kt * 64;
    ushort16* d = &LB[kt & 1][h * 8192 + wave * 512];
    gld16(g + off0, d);
    gld16(g + off1, d + 4096);
  };

  // fragment read offsets: row R at R*64 u16; k-chunk (ks*4+quad) XOR (R&7)
  const int slotk0 = ((0 * 4 + quad) ^ (l15 & 7)) * 8;
  const int slotk1 = ((1 * 4 + quad) ^ (l15 & 7)) * 8;

  short8 fragA[4][2];
  short8 b10[2], b11[2];          // B n2-3 frags (single-buffered)
  short8 b0a0[2], b0a1[2];        // B n0-1 frags, even tiles
  short8 b0b0[2], b0b1[2];        // B n0-1 frags, odd tiles
  floatx4 acc[8][4] = {};

#define G256_LDA(CA_, jm0)                                                    \
  do {                                                                        \
    _Pragma("unroll") for (int j = 0; j < 4; j++) {                           \
      const int R = (2 * ((jm0) + j) + wm) * 16 + l15;                        \
      fragA[j][0] = *(const short8*)((CA_) + R * 64 + slotk0);                \
      fragA[j][1] = *(const short8*)((CA_) + R * 64 + slotk1);                \
    }                                                                         \
  } while (0)

#define G256_LDB(LB_, jn0, D0, D1)                                            \
  do {                                                                        \
    { const int R = (4 * (jn0) + wn) * 16 + l15;                              \
      D0[0] = *(const short8*)((LB_) + R * 64 + slotk0);                      \
      D0[1] = *(const short8*)((LB_) + R * 64 + slotk1); }                    \
    { const int R = (4 * ((jn0) + 1) + wn) * 16 + l15;                        \
      D1[0] = *(const short8*)((LB_) + R * 64 + slotk0);                      \
      D1[1] = *(const short8*)((LB_) + R * 64 + slotk1); }                    \
  } while (0)

#define G256_MM(jm0, jn0, B0, B1)                                             \
  do {                                                                        \
    __builtin_amdgcn_s_setprio(1);                                            \
    _Pragma("unroll") for (int j = 0; j < 4; j++) {                           \
      acc[(jm0) + j][(jn0)] =                                                 \
          __builtin_amdgcn_mfma_f32_16x16x32_bf16(fragA[j][0], B0[0], acc[(jm0) + j][(jn0)], 0, 0, 0); \
      acc[(jm0) + j][(jn0)] =                                                 \
          __builtin_amdgcn_mfma_f32_16x16x32_bf16(fragA[j][1], B0[1], acc[(jm0) + j][(jn0)], 0, 0, 0); \
      acc[(jm0) + j][(jn0) + 1] =                                             \
          __builtin_amdgcn_mfma_f32_16x16x32_bf16(fragA[j][0], B1[0], acc[(jm0) + j][(jn0) + 1], 0, 0, 0); \
      acc[(jm0) + j][(jn0) + 1] =                                             \
          __builtin_amdgcn_mfma_f32_16x16x32_bf16(fragA[j][1], B1[1], acc[(jm0) + j][(jn0) + 1], 0, 0, 0); \
    }                                                                         \
    __builtin_amdgcn_s_setprio(0);                                            \
  } while (0)

#define BARRIER __builtin_amdgcn_s_barrier()
#define LGK0 do { asm volatile("s_waitcnt lgkmcnt(0)" ::: "memory");          \
                  __builtin_amdgcn_sched_barrier(0); } while (0)
#define VMC(t) do {                                                           \
    if ((t) < NT - 2) asm volatile("s_waitcnt vmcnt(6)" ::: "memory");        \
    else              asm volatile("s_waitcnt vmcnt(0)" ::: "memory");        \
  } while (0)

#define G256_TILE(t, C0, C1, N0, N1)                                          \
  do {                                                                        \
    const ushort16* CA_ = &LA[(t) & 1][0];                                    \
    const ushort16* CB_ = &LB[(t) & 1][0];                                    \
    /* P1: 8 reads (A m0-3) */                                                \
    G256_LDA(CA_, 0);                                                         \
    if ((t) + 1 < NT) STG_A((t) + 1, 0);                                      \
    BARRIER; LGK0;                                                            \
    G256_MM(0, 0, C0, C1);                                                    \
    VMC(t); BARRIER;                                                          \
    /* P2: 4 reads (B n2-3) */                                                \
    G256_LDB(CB_, 2, b10, b11);                                               \
    if ((t) + 1 < NT) STG_B((t) + 1, 1);                                      \
    BARRIER; LGK0;                                                            \
    G256_MM(0, 2, b10, b11);                                                  \
    VMC(t); BARRIER;                                                          \
    /* P3: 8 reads (A m4-7) */                                                \
    G256_LDA(CA_, 4);                                                         \
    if ((t) + 1 < NT) STG_A((t) + 1, 1);                                      \
    BARRIER; LGK0;                                                            \
    G256_MM(4, 2, b10, b11);                                                  \
    VMC(t); BARRIER;                                                          \
    /* P4: 4 reads (B n0-1 of tile t+1, other reg bank); MM uses old bank */  \
    if ((t) + 1 < NT) G256_LDB(&LB[((t) + 1) & 1][0], 0, N0, N1);             \
    if ((t) + 2 < NT) STG_B((t) + 2, 0);                                      \
    BARRIER;                                                                  \
    G256_MM(4, 0, C0, C1);                                                    \
    VMC(t); BARRIER;                                                          \
  } while (0)

  // prologue: B0(0)+A0(0) staged+drained; fB0(even) read; 3 half-tiles issued
  STG_B(0, 0);
  STG_A(0, 0);
  asm volatile("s_waitcnt vmcnt(0)" ::: "memory");
  BARRIER;
  G256_LDB(&LB[0][0], 0, b0a0, b0a1);
  STG_B(0, 1);
  STG_A(0, 1);
  STG_B(1, 0);   // 6 loads outstanding = steady-state entry

#pragma unroll 1
  for (int t0 = 0; t0 < NT; t0 += 2) {
    G256_TILE(t0,     b0a0, b0a1, b0b0, b0b1);
    G256_TILE(t0 + 1, b0b0, b0b1, b0a0, b0a1);
  }

#undef G256_LDA
#undef G256_LDB
#undef G256_MM
#undef G256_TILE
#undef BARRIER
#undef LGK0
#undef VMC

  // epilogue: row = bm + (2jm+wm)*16 + quad*4 + r, col = bn + (4jn+wn)*16 + l15
#pragma unroll
  for (int jm = 0; jm < 8; jm++) {
#pragma unroll
    for (int jn = 0; jn < 4; jn++) {
      const int col = bn + (4 * jn + wn) * 16 + l15;
#pragma unroll
      for (int r = 0; r < 4; r++) {
        const int row = bm + (2 * jm + wm) * 16 + quad * 4 + r;
        float v = acc[jm][jn][r];
        if (ROPE) {
          float other = __shfl_xor(v, 1, 64);
          const int pos = row & (S_ - 1);
          const int i   = (col & (HD_ - 1)) >> 1;
          const float c  = cosT[pos * (HD_ / 2) + i];
          const float sn = sinT[pos * (HD_ / 2) + i];
          v = (lane & 1) ? (other * sn + v * c) : (v * c - other * sn);
        }
        if (SCALE) v *= (0.08838834764831845f * 1.4426950408889634f);
        if (OUTF32) ((float*)Y)[(size_t)row * N + col] = v;
        else        ((ushort16*)Y)[(size_t)row * N + col] = f32_bf16(v);
      }
    }
  }
}

// MFMA flash attention v5 (unchanged this round).
// grid (16, B*NH), 512 thr = 8 waves, 16 q-rows/wave (128 rows/block).
// Swapped QK^T; exp2-domain softmax; b64 P-writes; defer-max; 80KB LDS ->
// 2 blocks/CU; ~95 VGPR no spill.
__global__ __launch_bounds__(512, 4)
void flash_mfma(const ushort16* __restrict__ Qg, const ushort16* __restrict__ Kg,
                const ushort16* __restrict__ Vtg, ushort16* __restrict__ Cg)
{
  __shared__ __align__(16) ushort16 Ks[2][64 * 128];   // [key][dim], chunk-swizzled, 16 KB each
  __shared__ __align__(16) ushort16 VT[2][128 * 64];   // [dim][key], chunk-swizzled, 16 KB each
  __shared__ __align__(16) ushort16 Ps[8][16 * 64];    // per-wave P, chunk-swizzled, 2 KB each

  const int tid = threadIdx.x, wave = tid >> 6, lane = tid & 63;
  const int l15 = lane & 15, quad = lane >> 4;
  const int qb = 15 - (int)blockIdx.x;                 // longest blocks dispatch first (LPT)
  const int by = blockIdx.y;
  const int b = by >> 5, h = by & 31, kh = h >> 2;
  const int qrow0 = qb * 128 + wave * 16;

  // Q frags (B-operand; scale*log2e pre-folded): B[n=l15][k=quad*8+j]
  short8 aq[4];
  const ushort16* qbase = Qg + (size_t)(b * S_ + qrow0 + l15) * 4096 + h * 128 + quad * 8;
#pragma unroll
  for (int ks = 0; ks < 4; ks++) aq[ks] = *(const short8*)(qbase + ks * 32);

  int kOff[2], vOff[2];
#pragma unroll
  for (int it = 0; it < 2; it++) {
    const int s = it * 512 + tid;
    const int rK = s >> 4, cK = (s & 15) ^ (rK & 15);   // K tile: 64 rows x 16 chunks
    kOff[it] = rK * 1024 + cK * 8;
    const int dV = s >> 3, cV = (s & 7) ^ (dV & 7);     // VT tile: 128 rows x 8 chunks
    vOff[it] = dV * 4096 + cV * 8;
  }
  const ushort16* Kbase = Kg + (size_t)(b * S_) * 1024 + kh * 128;
  const ushort16* Vbase = Vtg + (size_t)(kh * 128) * 4096 + (size_t)b * S_;
  const int ktmax = 2 * qb + 1;

  auto STAGE = [&](int kt, int buf) {
    const ushort16* kg = Kbase + (size_t)kt * 65536;
    const ushort16* vg = Vbase + kt * 64;
#pragma unroll
    for (int it = 0; it < 2; it++) {
      gld16(kg + kOff[it], &Ks[buf][0] + it * 4096 + wave * 512);
      gld16(vg + vOff[it], &VT[buf][0] + it * 4096 + wave * 512);
    }
  };

  STAGE(0, 0);
  __syncthreads();   // drains vmcnt: buf0 ready

  floatx4 o_acc[8] = {};
  float m_i = -1e30f, l_i = 0.f;
  ushort16* Pw = &Ps[wave][0];

  for (int kt = 0; kt <= ktmax; ++kt) {
    const int cur = kt & 1;
    if (kt < ktmax) STAGE(kt + 1, cur ^ 1);   // issue next tile before compute
    const ushort16* KsC = &Ks[cur][0];
    const ushort16* VTC = &VT[cur][0];

    if (kt * 64 <= qrow0 + 15) {
      // S^T = K Q^T : A-frag from K LDS, B-frag = aq
      floatx4 st[4] = {};
      __builtin_amdgcn_s_setprio(1);
#pragma unroll
      for (int k4 = 0; k4 < 4; k4++)
#pragma unroll
        for (int ks = 0; ks < 4; ks++) {
          short8 ak = *(const short8*)(KsC + (k4 * 16 + l15) * 128 + (((ks * 4 + quad) ^ l15) * 8));
          st[k4] = __builtin_amdgcn_mfma_f32_16x16x32_bf16(ak, aq[ks], st[k4], 0, 0, 0);
        }
      __builtin_amdgcn_s_setprio(0);

      // causal mask: lane's q = qrow0+l15, keys = kt*64 + k4*16 + quad*4 + r
      if (kt * 64 + 63 > qrow0) {
        const int q = qrow0 + l15;
#pragma unroll
        for (int k4 = 0; k4 < 4; k4++) {
          const int key = kt * 64 + k4 * 16 + quad * 4;
#pragma unroll
          for (int r = 0; r < 4; r++)
            if (key + r > q) st[k4][r] = -1e30f;
        }
      }

      // row max: in-lane over 16 + cross-quad (2 shuffles)
      float mx = st[0][0];
#pragma unroll
      for (int k4 = 0; k4 < 4; k4++)
#pragma unroll
        for (int r = 0; r < 4; r++) mx = fmaxf(mx, st[k4][r]);
      mx = fmaxf(mx, __shfl_xor(mx, 16, 64));
      mx = fmaxf(mx, __shfl_xor(mx, 32, 64));

      // T13 defer-max (log2 units; P bounded by 2^8)
      if (!__all(mx - m_i <= 8.f)) {
        const float mn = fmaxf(m_i, mx);
        const float alpha = exp2_fast(m_i - mn);
        m_i = mn;
        l_i *= alpha;
        float ar[4];
#pragma unroll
        for (int r = 0; r < 4; r++) ar[r] = __shfl(alpha, quad * 4 + r, 64);
#pragma unroll
        for (int dt = 0; dt < 8; dt++)
#pragma unroll
          for (int r = 0; r < 4; r++) o_acc[dt][r] *= ar[r];
      }
      const float m = m_i;

      // P = exp2(S - m), pack 4 keys -> one ds_write_b64 (swizzled), row-sum in-lane
      float rs = 0.f;
#pragma unroll
      for (int k4 = 0; k4 < 4; k4++) {
        const float p0 = exp2_fast(st[k4][0] - m);
        const float p1 = exp2_fast(st[k4][1] - m);
        const float p2 = exp2_fast(st[k4][2] - m);
        const float p3 = exp2_fast(st[k4][3] - m);
        rs += (p0 + p1) + (p2 + p3);
        uintx2 w;
        w[0] = pk_bf16(p0, p1);
        w[1] = pk_bf16(p2, p3);
        *(uintx2*)(Pw + l15 * 64 + (((k4 * 2 + (quad >> 1)) ^ (l15 & 7)) * 8) + (quad & 1) * 4) = w;
      }
      rs += __shfl_xor(rs, 16, 64);
      rs += __shfl_xor(rs, 32, 64);
      l_i += rs;

      // O += P V (same-wave LDS W->R, DS in-order)
      __builtin_amdgcn_s_setprio(1);
#pragma unroll
      for (int ks2 = 0; ks2 < 2; ks2++) {
        short8 ap = *(const short8*)(Pw + l15 * 64 + (((ks2 * 4 + quad) ^ (l15 & 7)) * 8));
#pragma unroll
        for (int dt = 0; dt < 8; dt++) {
          short8 bv = *(const short8*)(VTC + (dt * 16 + l15) * 64 + (((ks2 * 4 + quad) ^ (l15 & 7)) * 8));
          o_acc[dt] = __builtin_amdgcn_mfma_f32_16x16x32_bf16(ap, bv, o_acc[dt], 0, 0, 0);
        }
      }
      __builtin_amdgcn_s_setprio(0);
    }
    __syncthreads();   // next buf staged; cur buf free to overwrite
  }

  const float linv = 1.f / l_i;
  float vr[4];
#pragma unroll
  for (int r = 0; r < 4; r++) vr[r] = __shfl(linv, quad * 4 + r, 64);
#pragma unroll
  for (int dt = 0; dt < 8; dt++)
#pragma unroll
    for (int r = 0; r < 4; r++)
      Cg[(size_t)(b * S_ + qrow0 + quad * 4 + r) * 4096 + h * 128 + dt * 16 + l15] =
          f32_bf16(o_acc[dt][r] * vr[r]);
}

extern "C" void kernel_launch(void* const* d_in, const int* in_sizes, int n_in,
                              void* d_out, int out_size, void* d_ws, size_t ws_size,
                              hipStream_t stream) {
  const float* hs   = (const float*)d_in[0];
  const float* cosT = (const float*)d_in[1];
  const float* sinT = (const float*)d_in[2];
  const float* Wq = (const float*)d_in[5];
  const float* Wk = (const float*)d_in[6];
  const float* Wv = (const float*)d_in[7];
  const float* Wo = (const float*)d_in[8];
  float* out = (float*)d_out;

  char* ws = (char*)d_ws;
  ushort16* hsB = (ushort16*)(ws);                      // 33.5 MB  (also reused as CB)
  ushort16* QB  = (ushort16*)(ws + 33554432);           // 33.5 MB
  ushort16* KB  = (ushort16*)(ws + 67108864);           // 8.4 MB
  ushort16* VB  = (ushort16*)(ws + 75497472);           // 8.4 MB
  ushort16* VTg = (ushort16*)(ws + 83886080);           // 8.4 MB
  ushort16* WB  = (ushort16*)(ws + 92274688);           // 33.5 MB (per-GEMM weight buf)
  ushort16* CB  = hsB;                                  // reuse hs region after V GEMM

  dim3 blk(256);
  cvt_bf16<<<dim3(16384), blk, 0, stream>>>(hs, (uint32*)hsB);
  cvt_bf16<<<dim3(16384), blk, 0, stream>>>(Wq, (uint32*)WB);
  gemm256<true,  true,  false><<<dim3(256), dim3(512), 0, stream>>>(hsB, WB, QB, 4096, cosT, sinT);
  cvt_bf16<<<dim3(4096),  blk, 0, stream>>>(Wk, (uint32*)WB);
  gemm128<true,  false, false><<<dim3(8, 32), blk, 0, stream>>>(hsB, WB, KB, 1024, cosT, sinT);
  cvt_bf16<<<dim3(4096),  blk, 0, stream>>>(Wv, (uint32*)WB);
  gemm128<false, false, false><<<dim3(8, 32), blk, 0, stream>>>(hsB, WB, VB, 1024, cosT, sinT);
  transp<<<dim3(16, 64), blk, 0, stream>>>(VB, VTg);
  flash_mfma<<<dim3(16, 2 * NH_), dim3(512), 0, stream>>>(QB, KB, VTg, CB);
  cvt_bf16<<<dim3(16384), blk, 0, stream>>>(Wo, (uint32*)WB);
  gemm256<false, false, true><<<dim3(256), dim3(512), 0, stream>>>(CB, WB, out, 4096, cosT, sinT);
}

// Round 7
// 744.572 us; speedup vs baseline: 1.0761x; 1.0761x over previous
//
#include <hip/hip_runtime.h>
#include <cstdint>

#define S_   2048
#define H_   4096
#define NH_  32
#define NKV_ 8
#define HD_  128

typedef short  short8  __attribute__((ext_vector_type(8)));
typedef float  floatx4 __attribute__((ext_vector_type(4)));
typedef unsigned int uintx2 __attribute__((ext_vector_type(2)));
typedef unsigned int uint32;
typedef unsigned short ushort16;

__device__ inline unsigned int pk_bf16(float a, float b) {
  unsigned int ua = __builtin_bit_cast(unsigned int, a) + 0x8000u;
  unsigned int ub = __builtin_bit_cast(unsigned int, b) + 0x8000u;
  return __builtin_amdgcn_perm(ub, ua, 0x07060302u);
}
__device__ inline unsigned short f32_bf16(float a) {
  return (unsigned short)((__builtin_bit_cast(unsigned int, a) + 0x8000u) >> 16);
}
__device__ inline float exp2_fast(float x) {
  float r; asm("v_exp_f32 %0, %1" : "=v"(r) : "v"(x)); return r;
}

__device__ inline void gld16(const ushort16* g, ushort16* l) {
  __builtin_amdgcn_global_load_lds((const __attribute__((address_space(1))) void*)g,
                                   (__attribute__((address_space(3))) void*)l, 16, 0, 0);
}

// fp32 -> bf16 elementwise, 4 elems/thread. grid = n/1024.
__global__ __launch_bounds__(256)
void cvt_bf16(const float* __restrict__ in, uint32* __restrict__ out) {
  const int idx = blockIdx.x * 256 + threadIdx.x;
  floatx4 v = ((const floatx4*)in)[idx];
  uintx2 o;
  o[0] = pk_bf16(v[0], v[1]);
  o[1] = pk_bf16(v[2], v[3]);
  ((uintx2*)out)[idx] = o;
}

// bf16 transpose: in [4096 x 1024] -> out [1024 x 4096]. grid (16, 64), 256 thr.
__global__ __launch_bounds__(256)
void transp(const ushort16* __restrict__ in, ushort16* __restrict__ out) {
  __shared__ __align__(16) ushort16 T[64 * 66];
  const int tid = threadIdx.x, wave = tid >> 6, j = tid & 63;
  const int c0 = blockIdx.x * 64, r0 = blockIdx.y * 64;
#pragma unroll
  for (int it = 0; it < 16; it++) {
    const int i = it * 4 + wave;
    T[i * 66 + j] = in[(size_t)(r0 + i) * 1024 + c0 + j];
  }
  __syncthreads();
#pragma unroll
  for (int it = 0; it < 16; it++) {
    const int i = it * 4 + wave;
    out[(size_t)(c0 + i) * 4096 + r0 + j] = T[j * 66 + i];
  }
}

// Fused K+V projection: Y(4096 x 2048) = hsB @ [Wk;Wv]^T, m97-style 128x128 tile.
// grid (16,32) = 512 wg = 2 blocks/CU (the N=1024 split ran 256 wg = 1 block/CU,
// fully exposing the per-K-step barrier drain -> ~250 TF; 2 blocks/CU restores
// the m114 cross-block overlap). Epilogue: cols <1024 = K half (RoPE, exp2-scale
// NOT applied - only Q carries scale), cols >=1024 = V half (plain), routed to
// separate KB / VB buffers. Per-element numerics identical to the split version.
__global__ __launch_bounds__(256)
void gemm128_kv(const ushort16* __restrict__ A, const ushort16* __restrict__ B,
                ushort16* __restrict__ Kout, ushort16* __restrict__ Vout,
                const float* __restrict__ cosT, const float* __restrict__ sinT)
{
  constexpr int K = H_;
  __shared__ __align__(16) ushort16 As[128 * 32];
  __shared__ __align__(16) ushort16 Bs[128 * 32];
  const int bn = blockIdx.x * 128, bm = blockIdx.y * 128;
  const int tid = threadIdx.x, wave = tid >> 6, lane = tid & 63;
  const int l15 = lane & 15, quad = lane >> 4;
  const int wr = (wave & 1) * 64, wc = (wave >> 1) * 64;

  const int crow = lane >> 2;
  const int ckb  = (lane & 3) ^ ((lane >> 3) & 3);
  const int q0 = wave * 2, q1 = q0 + 1;
  const ushort16* gA0 = A + (size_t)(bm + q0 * 16 + crow) * K + ckb * 8;
  const ushort16* gA1 = A + (size_t)(bm + q1 * 16 + crow) * K + ckb * 8;
  const ushort16* gB0 = B + (size_t)(bn + q0 * 16 + crow) * K + ckb * 8;
  const ushort16* gB1 = B + (size_t)(bn + q1 * 16 + crow) * K + ckb * 8;
  ushort16* lA0 = As + q0 * 512;
  ushort16* lA1 = As + q1 * 512;
  ushort16* lB0 = Bs + q0 * 512;
  ushort16* lB1 = Bs + q1 * 512;

  const int slot = quad ^ ((l15 >> 1) & 3);
  int aoff[4], boff[4];
#pragma unroll
  for (int t = 0; t < 4; t++) {
    aoff[t] = (wr + t * 16 + l15) * 32 + slot * 8;
    boff[t] = (wc + t * 16 + l15) * 32 + slot * 8;
  }

  floatx4 acc[4][4] = {};

  for (int k0 = 0; k0 < K; k0 += 32) {
    __syncthreads();
    gld16(gA0 + k0, lA0);
    gld16(gA1 + k0, lA1);
    gld16(gB0 + k0, lB0);
    gld16(gB1 + k0, lB1);
    __syncthreads();

    short8 af[4], bf[4];
#pragma unroll
    for (int t = 0; t < 4; t++) af[t] = *(const short8*)(As + aoff[t]);
#pragma unroll
    for (int t = 0; t < 4; t++) bf[t] = *(const short8*)(Bs + boff[t]);
#pragma unroll
    for (int mt = 0; mt < 4; mt++)
#pragma unroll
      for (int nt = 0; nt < 4; nt++)
        acc[mt][nt] = __builtin_amdgcn_mfma_f32_16x16x32_bf16(af[mt], bf[nt], acc[mt][nt], 0, 0, 0);
  }

#pragma unroll
  for (int mt = 0; mt < 4; mt++) {
#pragma unroll
    for (int nt = 0; nt < 4; nt++) {
      const int col = bn + wc + nt * 16 + l15;
#pragma unroll
      for (int r = 0; r < 4; r++) {
        const int row = bm + wr + mt * 16 + quad * 4 + r;
        float v = acc[mt][nt][r];
        // RoPE pair shuffle (uniform across lanes; used only by the K half)
        float other = __shfl_xor(v, 1, 64);
        const int pos = row & (S_ - 1);
        const int i   = (col & (HD_ - 1)) >> 1;
        const float c  = cosT[pos * (HD_ / 2) + i];
        const float sn = sinT[pos * (HD_ / 2) + i];
        const float vk = (lane & 1) ? (other * sn + v * c) : (v * c - other * sn);
        if (col < 1024) Kout[(size_t)row * 1024 + col]        = f32_bf16(vk);
        else            Vout[(size_t)row * 1024 + col - 1024] = f32_bf16(v);
      }
    }
  }
}

// 256x256-tile 8-phase/2-K-tile GEMM (m201-port, T2+T3+T4+T5), N=4096 GEMMs.
// Reads balanced 8,4,8,4 per phase via a register double-buffer for the
// B(n0-1) fragments (static reg indexing, rule #20). Uniform vmcnt(6) at every
// phase end (4 half-tiles = 8 loads in flight; 3-half-tile lead; drained only
// on the last 2 K-tiles). Staging map (tile t): P1->A0(t+1), P2->B1(t+1),
// P3->A1(t+1), P4->B0(t+2); every overwrite >=4 phases after last read.
template<bool ROPE, bool SCALE, bool OUTF32>
__global__ __launch_bounds__(512, 2)
void gemm256(const ushort16* __restrict__ A, const ushort16* __restrict__ B,
             void* __restrict__ Y, int N,
             const float* __restrict__ cosT, const float* __restrict__ sinT)
{
  constexpr int NT = H_ / 64;                      // 64 K-tiles
  __shared__ __align__(16) ushort16 LA[2][16384];  // [buf][256 rows x 64 k] bf16, 32KB
  __shared__ __align__(16) ushort16 LB[2][16384];

  // XCD-bijective swizzle (gridDim.x = 256, divisible by 8)
  const int bid = (int)blockIdx.x;
  const int wg  = (bid & 7) * ((int)gridDim.x >> 3) + (bid >> 3);
  const int nbx = N >> 8;
  const int bm = (wg / nbx) * 256, bn = (wg % nbx) * 256;

  const int tid = threadIdx.x, wave = tid >> 6, lane = tid & 63;
  const int l15 = lane & 15, quad = lane >> 4;
  const int wm = wave >> 2, wn = wave & 3;

  const int s1 = 512 + tid;
  const int off0 = (tid >> 3) * 4096 + (((tid & 7) ^ ((tid >> 3) & 7)) * 8);
  const int off1 = (s1  >> 3) * 4096 + (((s1  & 7) ^ ((s1  >> 3) & 7)) * 8);

  auto STG_A = [&](int kt, int h) {
    const ushort16* g = A + (size_t)(bm + h * 128) * 4096 + kt * 64;
    ushort16* d = &LA[kt & 1][h * 8192 + wave * 512];
    gld16(g + off0, d);
    gld16(g + off1, d + 4096);
  };
  auto STG_B = [&](int kt, int h) {
    const ushort16* g = B + (size_t)(bn + h * 128) * 4096 + kt * 64;
    ushort16* d = &LB[kt & 1][h * 8192 + wave * 512];
    gld16(g + off0, d);
    gld16(g + off1, d + 4096);
  };

  const int slotk0 = ((0 * 4 + quad) ^ (l15 & 7)) * 8;
  const int slotk1 = ((1 * 4 + quad) ^ (l15 & 7)) * 8;

  short8 fragA[4][2];
  short8 b10[2], b11[2];          // B n2-3 frags (single-buffered)
  short8 b0a0[2], b0a1[2];        // B n0-1 frags, even tiles
  short8 b0b0[2], b0b1[2];        // B n0-1 frags, odd tiles
  floatx4 acc[8][4] = {};

#define G256_LDA(CA_, jm0)                                                    \
  do {                                                                        \
    _Pragma("unroll") for (int j = 0; j < 4; j++) {                           \
      const int R = (2 * ((jm0) + j) + wm) * 16 + l15;                        \
      fragA[j][0] = *(const short8*)((CA_) + R * 64 + slotk0);                \
      fragA[j][1] = *(const short8*)((CA_) + R * 64 + slotk1);                \
    }                                                                         \
  } while (0)

#define G256_LDB(LB_, jn0, D0, D1)                                            \
  do {                                                                        \
    { const int R = (4 * (jn0) + wn) * 16 + l15;                              \
      D0[0] = *(const short8*)((LB_) + R * 64 + slotk0);                      \
      D0[1] = *(const short8*)((LB_) + R * 64 + slotk1); }                    \
    { const int R = (4 * ((jn0) + 1) + wn) * 16 + l15;                        \
      D1[0] = *(const short8*)((LB_) + R * 64 + slotk0);                      \
      D1[1] = *(const short8*)((LB_) + R * 64 + slotk1); }                    \
  } while (0)

#define G256_MM(jm0, jn0, B0, B1)                                             \
  do {                                                                        \
    __builtin_amdgcn_s_setprio(1);                                            \
    _Pragma("unroll") for (int j = 0; j < 4; j++) {                           \
      acc[(jm0) + j][(jn0)] =                                                 \
          __builtin_amdgcn_mfma_f32_16x16x32_bf16(fragA[j][0], B0[0], acc[(jm0) + j][(jn0)], 0, 0, 0); \
      acc[(jm0) + j][(jn0)] =                                                 \
          __builtin_amdgcn_mfma_f32_16x16x32_bf16(fragA[j][1], B0[1], acc[(jm0) + j][(jn0)], 0, 0, 0); \
      acc[(jm0) + j][(jn0) + 1] =                                             \
          __builtin_amdgcn_mfma_f32_16x16x32_bf16(fragA[j][0], B1[0], acc[(jm0) + j][(jn0) + 1], 0, 0, 0); \
      acc[(jm0) + j][(jn0) + 1] =                                             \
          __builtin_amdgcn_mfma_f32_16x16x32_bf16(fragA[j][1], B1[1], acc[(jm0) + j][(jn0) + 1], 0, 0, 0); \
    }                                                                         \
    __builtin_amdgcn_s_setprio(0);                                            \
  } while (0)

#define BARRIER __builtin_amdgcn_s_barrier()
#define LGK0 do { asm volatile("s_waitcnt lgkmcnt(0)" ::: "memory");          \
                  __builtin_amdgcn_sched_barrier(0); } while (0)
#define VMC(t) do {                                                           \
    if ((t) < NT - 2) asm volatile("s_waitcnt vmcnt(6)" ::: "memory");        \
    else              asm volatile("s_waitcnt vmcnt(0)" ::: "memory");        \
  } while (0)

#define G256_TILE(t, C0, C1, N0, N1)                                          \
  do {                                                                        \
    const ushort16* CA_ = &LA[(t) & 1][0];                                    \
    const ushort16* CB_ = &LB[(t) & 1][0];                                    \
    /* P1: 8 reads (A m0-3) */                                                \
    G256_LDA(CA_, 0);                                                         \
    if ((t) + 1 < NT) STG_A((t) + 1, 0);                                      \
    BARRIER; LGK0;                                                            \
    G256_MM(0, 0, C0, C1);                                                    \
    VMC(t); BARRIER;                                                          \
    /* P2: 4 reads (B n2-3) */                                                \
    G256_LDB(CB_, 2, b10, b11);                                               \
    if ((t) + 1 < NT) STG_B((t) + 1, 1);                                      \
    BARRIER; LGK0;                                                            \
    G256_MM(0, 2, b10, b11);                                                  \
    VMC(t); BARRIER;                                                          \
    /* P3: 8 reads (A m4-7) */                                                \
    G256_LDA(CA_, 4);                                                         \
    if ((t) + 1 < NT) STG_A((t) + 1, 1);                                      \
    BARRIER; LGK0;                                                            \
    G256_MM(4, 2, b10, b11);                                                  \
    VMC(t); BARRIER;                                                          \
    /* P4: 4 reads (B n0-1 of tile t+1, other reg bank); MM uses old bank */  \
    if ((t) + 1 < NT) G256_LDB(&LB[((t) + 1) & 1][0], 0, N0, N1);             \
    if ((t) + 2 < NT) STG_B((t) + 2, 0);                                      \
    BARRIER;                                                                  \
    G256_MM(4, 0, C0, C1);                                                    \
    VMC(t); BARRIER;                                                          \
  } while (0)

  // prologue: B0(0)+A0(0) staged+drained; fB0(even) read; 3 half-tiles issued
  STG_B(0, 0);
  STG_A(0, 0);
  asm volatile("s_waitcnt vmcnt(0)" ::: "memory");
  BARRIER;
  G256_LDB(&LB[0][0], 0, b0a0, b0a1);
  STG_B(0, 1);
  STG_A(0, 1);
  STG_B(1, 0);   // 6 loads outstanding = steady-state entry

#pragma unroll 1
  for (int t0 = 0; t0 < NT; t0 += 2) {
    G256_TILE(t0,     b0a0, b0a1, b0b0, b0b1);
    G256_TILE(t0 + 1, b0b0, b0b1, b0a0, b0a1);
  }

#undef G256_LDA
#undef G256_LDB
#undef G256_MM
#undef G256_TILE
#undef BARRIER
#undef LGK0
#undef VMC

  // epilogue: row = bm + (2jm+wm)*16 + quad*4 + r, col = bn + (4jn+wn)*16 + l15
#pragma unroll
  for (int jm = 0; jm < 8; jm++) {
#pragma unroll
    for (int jn = 0; jn < 4; jn++) {
      const int col = bn + (4 * jn + wn) * 16 + l15;
#pragma unroll
      for (int r = 0; r < 4; r++) {
        const int row = bm + (2 * jm + wm) * 16 + quad * 4 + r;
        float v = acc[jm][jn][r];
        if (ROPE) {
          float other = __shfl_xor(v, 1, 64);
          const int pos = row & (S_ - 1);
          const int i   = (col & (HD_ - 1)) >> 1;
          const float c  = cosT[pos * (HD_ / 2) + i];
          const float sn = sinT[pos * (HD_ / 2) + i];
          v = (lane & 1) ? (other * sn + v * c) : (v * c - other * sn);
        }
        if (SCALE) v *= (0.08838834764831845f * 1.4426950408889634f);
        if (OUTF32) ((float*)Y)[(size_t)row * N + col] = v;
        else        ((ushort16*)Y)[(size_t)row * N + col] = f32_bf16(v);
      }
    }
  }
}

// MFMA flash attention v5 (unchanged).
// grid (16, B*NH), 512 thr = 8 waves, 16 q-rows/wave (128 rows/block).
// Swapped QK^T; exp2-domain softmax; b64 P-writes; defer-max; 80KB LDS ->
// 2 blocks/CU; ~95 VGPR no spill.
__global__ __launch_bounds__(512, 4)
void flash_mfma(const ushort16* __restrict__ Qg, const ushort16* __restrict__ Kg,
                const ushort16* __restrict__ Vtg, ushort16* __restrict__ Cg)
{
  __shared__ __align__(16) ushort16 Ks[2][64 * 128];   // [key][dim], chunk-swizzled, 16 KB each
  __shared__ __align__(16) ushort16 VT[2][128 * 64];   // [dim][key], chunk-swizzled, 16 KB each
  __shared__ __align__(16) ushort16 Ps[8][16 * 64];    // per-wave P, chunk-swizzled, 2 KB each

  const int tid = threadIdx.x, wave = tid >> 6, lane = tid & 63;
  const int l15 = lane & 15, quad = lane >> 4;
  const int qb = 15 - (int)blockIdx.x;                 // longest blocks dispatch first (LPT)
  const int by = blockIdx.y;
  const int b = by >> 5, h = by & 31, kh = h >> 2;
  const int qrow0 = qb * 128 + wave * 16;

  // Q frags (B-operand; scale*log2e pre-folded): B[n=l15][k=quad*8+j]
  short8 aq[4];
  const ushort16* qbase = Qg + (size_t)(b * S_ + qrow0 + l15) * 4096 + h * 128 + quad * 8;
#pragma unroll
  for (int ks = 0; ks < 4; ks++) aq[ks] = *(const short8*)(qbase + ks * 32);

  int kOff[2], vOff[2];
#pragma unroll
  for (int it = 0; it < 2; it++) {
    const int s = it * 512 + tid;
    const int rK = s >> 4, cK = (s & 15) ^ (rK & 15);   // K tile: 64 rows x 16 chunks
    kOff[it] = rK * 1024 + cK * 8;
    const int dV = s >> 3, cV = (s & 7) ^ (dV & 7);     // VT tile: 128 rows x 8 chunks
    vOff[it] = dV * 4096 + cV * 8;
  }
  const ushort16* Kbase = Kg + (size_t)(b * S_) * 1024 + kh * 128;
  const ushort16* Vbase = Vtg + (size_t)(kh * 128) * 4096 + (size_t)b * S_;
  const int ktmax = 2 * qb + 1;

  auto STAGE = [&](int kt, int buf) {
    const ushort16* kg = Kbase + (size_t)kt * 65536;
    const ushort16* vg = Vbase + kt * 64;
#pragma unroll
    for (int it = 0; it < 2; it++) {
      gld16(kg + kOff[it], &Ks[buf][0] + it * 4096 + wave * 512);
      gld16(vg + vOff[it], &VT[buf][0] + it * 4096 + wave * 512);
    }
  };

  STAGE(0, 0);
  __syncthreads();   // drains vmcnt: buf0 ready

  floatx4 o_acc[8] = {};
  float m_i = -1e30f, l_i = 0.f;
  ushort16* Pw = &Ps[wave][0];

  for (int kt = 0; kt <= ktmax; ++kt) {
    const int cur = kt & 1;
    if (kt < ktmax) STAGE(kt + 1, cur ^ 1);   // issue next tile before compute
    const ushort16* KsC = &Ks[cur][0];
    const ushort16* VTC = &VT[cur][0];

    if (kt * 64 <= qrow0 + 15) {
      // S^T = K Q^T : A-frag from K LDS, B-frag = aq
      floatx4 st[4] = {};
      __builtin_amdgcn_s_setprio(1);
#pragma unroll
      for (int k4 = 0; k4 < 4; k4++)
#pragma unroll
        for (int ks = 0; ks < 4; ks++) {
          short8 ak = *(const short8*)(KsC + (k4 * 16 + l15) * 128 + (((ks * 4 + quad) ^ l15) * 8));
          st[k4] = __builtin_amdgcn_mfma_f32_16x16x32_bf16(ak, aq[ks], st[k4], 0, 0, 0);
        }
      __builtin_amdgcn_s_setprio(0);

      // causal mask: lane's q = qrow0+l15, keys = kt*64 + k4*16 + quad*4 + r
      if (kt * 64 + 63 > qrow0) {
        const int q = qrow0 + l15;
#pragma unroll
        for (int k4 = 0; k4 < 4; k4++) {
          const int key = kt * 64 + k4 * 16 + quad * 4;
#pragma unroll
          for (int r = 0; r < 4; r++)
            if (key + r > q) st[k4][r] = -1e30f;
        }
      }

      // row max: in-lane over 16 + cross-quad (2 shuffles)
      float mx = st[0][0];
#pragma unroll
      for (int k4 = 0; k4 < 4; k4++)
#pragma unroll
        for (int r = 0; r < 4; r++) mx = fmaxf(mx, st[k4][r]);
      mx = fmaxf(mx, __shfl_xor(mx, 16, 64));
      mx = fmaxf(mx, __shfl_xor(mx, 32, 64));

      // T13 defer-max (log2 units; P bounded by 2^8)
      if (!__all(mx - m_i <= 8.f)) {
        const float mn = fmaxf(m_i, mx);
        const float alpha = exp2_fast(m_i - mn);
        m_i = mn;
        l_i *= alpha;
        float ar[4];
#pragma unroll
        for (int r = 0; r < 4; r++) ar[r] = __shfl(alpha, quad * 4 + r, 64);
#pragma unroll
        for (int dt = 0; dt < 8; dt++)
#pragma unroll
          for (int r = 0; r < 4; r++) o_acc[dt][r] *= ar[r];
      }
      const float m = m_i;

      // P = exp2(S - m), pack 4 keys -> one ds_write_b64 (swizzled), row-sum in-lane
      float rs = 0.f;
#pragma unroll
      for (int k4 = 0; k4 < 4; k4++) {
        const float p0 = exp2_fast(st[k4][0] - m);
        const float p1 = exp2_fast(st[k4][1] - m);
        const float p2 = exp2_fast(st[k4][2] - m);
        const float p3 = exp2_fast(st[k4][3] - m);
        rs += (p0 + p1) + (p2 + p3);
        uintx2 w;
        w[0] = pk_bf16(p0, p1);
        w[1] = pk_bf16(p2, p3);
        *(uintx2*)(Pw + l15 * 64 + (((k4 * 2 + (quad >> 1)) ^ (l15 & 7)) * 8) + (quad & 1) * 4) = w;
      }
      rs += __shfl_xor(rs, 16, 64);
      rs += __shfl_xor(rs, 32, 64);
      l_i += rs;

      // O += P V (same-wave LDS W->R, DS in-order)
      __builtin_amdgcn_s_setprio(1);
#pragma unroll
      for (int ks2 = 0; ks2 < 2; ks2++) {
        short8 ap = *(const short8*)(Pw + l15 * 64 + (((ks2 * 4 + quad) ^ (l15 & 7)) * 8));
#pragma unroll
        for (int dt = 0; dt < 8; dt++) {
          short8 bv = *(const short8*)(VTC + (dt * 16 + l15) * 64 + (((ks2 * 4 + quad) ^ (l15 & 7)) * 8));
          o_acc[dt] = __builtin_amdgcn_mfma_f32_16x16x32_bf16(ap, bv, o_acc[dt], 0, 0, 0);
        }
      }
      __builtin_amdgcn_s_setprio(0);
    }
    __syncthreads();   // next buf staged; cur buf free to overwrite
  }

  const float linv = 1.f / l_i;
  float vr[4];
#pragma unroll
  for (int r = 0; r < 4; r++) vr[r] = __shfl(linv, quad * 4 + r, 64);
#pragma unroll
  for (int dt = 0; dt < 8; dt++)
#pragma unroll
    for (int r = 0; r < 4; r++)
      Cg[(size_t)(b * S_ + qrow0 + quad * 4 + r) * 4096 + h * 128 + dt * 16 + l15] =
          f32_bf16(o_acc[dt][r] * vr[r]);
}

extern "C" void kernel_launch(void* const* d_in, const int* in_sizes, int n_in,
                              void* d_out, int out_size, void* d_ws, size_t ws_size,
                              hipStream_t stream) {
  const float* hs   = (const float*)d_in[0];
  const float* cosT = (const float*)d_in[1];
  const float* sinT = (const float*)d_in[2];
  const float* Wq = (const float*)d_in[5];
  const float* Wk = (const float*)d_in[6];
  const float* Wv = (const float*)d_in[7];
  const float* Wo = (const float*)d_in[8];
  float* out = (float*)d_out;

  char* ws = (char*)d_ws;
  ushort16* hsB = (ushort16*)(ws);                      // 33.5 MB  (also reused as CB)
  ushort16* QB  = (ushort16*)(ws + 33554432);           // 33.5 MB
  ushort16* KB  = (ushort16*)(ws + 67108864);           // 8.4 MB
  ushort16* VB  = (ushort16*)(ws + 75497472);           // 8.4 MB
  ushort16* VTg = (ushort16*)(ws + 83886080);           // 8.4 MB
  ushort16* WB  = (ushort16*)(ws + 92274688);           // 33.5 MB (per-GEMM weight buf; KV: [Wk;Wv] stacked)
  ushort16* CB  = hsB;                                  // reuse hs region after KV GEMM

  dim3 blk(256);
  cvt_bf16<<<dim3(16384), blk, 0, stream>>>(hs, (uint32*)hsB);
  cvt_bf16<<<dim3(16384), blk, 0, stream>>>(Wq, (uint32*)WB);
  gemm256<true,  true,  false><<<dim3(256), dim3(512), 0, stream>>>(hsB, WB, QB, 4096, cosT, sinT);
  // fused K+V projection: WB = [Wk (rows 0-1023); Wv (rows 1024-2047)]
  cvt_bf16<<<dim3(4096),  blk, 0, stream>>>(Wk, (uint32*)WB);
  cvt_bf16<<<dim3(4096),  blk, 0, stream>>>(Wv, (uint32*)(WB + 4194304));
  gemm128_kv<<<dim3(16, 32), blk, 0, stream>>>(hsB, WB, KB, VB, cosT, sinT);
  transp<<<dim3(16, 64), blk, 0, stream>>>(VB, VTg);
  flash_mfma<<<dim3(16, 2 * NH_), dim3(512), 0, stream>>>(QB, KB, VTg, CB);
  cvt_bf16<<<dim3(16384), blk, 0, stream>>>(Wo, (uint32*)WB);
  gemm256<false, false, true><<<dim3(256), dim3(512), 0, stream>>>(CB, WB, out, 4096, cosT, sinT);
}

// Round 8
// 703.534 us; speedup vs baseline: 1.1389x; 1.0583x over previous
//
#include <hip/hip_runtime.h>
#include <cstdint>

#define S_   2048
#define H_   4096
#define NH_  32
#define NKV_ 8
#define HD_  128

typedef short  short8  __attribute__((ext_vector_type(8)));
typedef float  floatx4 __attribute__((ext_vector_type(4)));
typedef unsigned int uintx2 __attribute__((ext_vector_type(2)));
typedef unsigned int uint32;
typedef unsigned short ushort16;

__device__ inline unsigned int pk_bf16(float a, float b) {
  unsigned int ua = __builtin_bit_cast(unsigned int, a) + 0x8000u;
  unsigned int ub = __builtin_bit_cast(unsigned int, b) + 0x8000u;
  return __builtin_amdgcn_perm(ub, ua, 0x07060302u);
}
__device__ inline unsigned short f32_bf16(float a) {
  return (unsigned short)((__builtin_bit_cast(unsigned int, a) + 0x8000u) >> 16);
}
__device__ inline float exp2_fast(float x) {
  float r; asm("v_exp_f32 %0, %1" : "=v"(r) : "v"(x)); return r;
}

__device__ inline void gld16(const ushort16* g, ushort16* l) {
  __builtin_amdgcn_global_load_lds((const __attribute__((address_space(1))) void*)g,
                                   (__attribute__((address_space(3))) void*)l, 16, 0, 0);
}

// fp32 -> bf16 elementwise, 4 elems/thread. grid = n/1024.
__global__ __launch_bounds__(256)
void cvt_bf16(const float* __restrict__ in, uint32* __restrict__ out) {
  const int idx = blockIdx.x * 256 + threadIdx.x;
  floatx4 v = ((const floatx4*)in)[idx];
  uintx2 o;
  o[0] = pk_bf16(v[0], v[1]);
  o[1] = pk_bf16(v[2], v[3]);
  ((uintx2*)out)[idx] = o;
}

// bf16 transpose: in [4096 x 1024] -> out [1024 x 4096]. grid (16, 64), 256 thr.
__global__ __launch_bounds__(256)
void transp(const ushort16* __restrict__ in, ushort16* __restrict__ out) {
  __shared__ __align__(16) ushort16 T[64 * 66];
  const int tid = threadIdx.x, wave = tid >> 6, j = tid & 63;
  const int c0 = blockIdx.x * 64, r0 = blockIdx.y * 64;
#pragma unroll
  for (int it = 0; it < 16; it++) {
    const int i = it * 4 + wave;
    T[i * 66 + j] = in[(size_t)(r0 + i) * 1024 + c0 + j];
  }
  __syncthreads();
#pragma unroll
  for (int it = 0; it < 16; it++) {
    const int i = it * 4 + wave;
    out[(size_t)(c0 + i) * 4096 + r0 + j] = T[j * 66 + i];
  }
}

// Fused K+V projection: Y(4096 x 2048) = hsB @ [Wk;Wv]^T, m97-style 128x128 tile.
// grid (16,32) = 512 wg = 2 blocks/CU. Epilogue: cols <1024 = K half (RoPE),
// cols >=1024 = V half (plain), routed to separate KB / VB buffers.
__global__ __launch_bounds__(256)
void gemm128_kv(const ushort16* __restrict__ A, const ushort16* __restrict__ B,
                ushort16* __restrict__ Kout, ushort16* __restrict__ Vout,
                const float* __restrict__ cosT, const float* __restrict__ sinT)
{
  constexpr int K = H_;
  __shared__ __align__(16) ushort16 As[128 * 32];
  __shared__ __align__(16) ushort16 Bs[128 * 32];
  const int bn = blockIdx.x * 128, bm = blockIdx.y * 128;
  const int tid = threadIdx.x, wave = tid >> 6, lane = tid & 63;
  const int l15 = lane & 15, quad = lane >> 4;
  const int wr = (wave & 1) * 64, wc = (wave >> 1) * 64;

  const int crow = lane >> 2;
  const int ckb  = (lane & 3) ^ ((lane >> 3) & 3);
  const int q0 = wave * 2, q1 = q0 + 1;
  const ushort16* gA0 = A + (size_t)(bm + q0 * 16 + crow) * K + ckb * 8;
  const ushort16* gA1 = A + (size_t)(bm + q1 * 16 + crow) * K + ckb * 8;
  const ushort16* gB0 = B + (size_t)(bn + q0 * 16 + crow) * K + ckb * 8;
  const ushort16* gB1 = B + (size_t)(bn + q1 * 16 + crow) * K + ckb * 8;
  ushort16* lA0 = As + q0 * 512;
  ushort16* lA1 = As + q1 * 512;
  ushort16* lB0 = Bs + q0 * 512;
  ushort16* lB1 = Bs + q1 * 512;

  const int slot = quad ^ ((l15 >> 1) & 3);
  int aoff[4], boff[4];
#pragma unroll
  for (int t = 0; t < 4; t++) {
    aoff[t] = (wr + t * 16 + l15) * 32 + slot * 8;
    boff[t] = (wc + t * 16 + l15) * 32 + slot * 8;
  }

  floatx4 acc[4][4] = {};

  for (int k0 = 0; k0 < K; k0 += 32) {
    __syncthreads();
    gld16(gA0 + k0, lA0);
    gld16(gA1 + k0, lA1);
    gld16(gB0 + k0, lB0);
    gld16(gB1 + k0, lB1);
    __syncthreads();

    short8 af[4], bf[4];
#pragma unroll
    for (int t = 0; t < 4; t++) af[t] = *(const short8*)(As + aoff[t]);
#pragma unroll
    for (int t = 0; t < 4; t++) bf[t] = *(const short8*)(Bs + boff[t]);
#pragma unroll
    for (int mt = 0; mt < 4; mt++)
#pragma unroll
      for (int nt = 0; nt < 4; nt++)
        acc[mt][nt] = __builtin_amdgcn_mfma_f32_16x16x32_bf16(af[mt], bf[nt], acc[mt][nt], 0, 0, 0);
  }

#pragma unroll
  for (int mt = 0; mt < 4; mt++) {
#pragma unroll
    for (int nt = 0; nt < 4; nt++) {
      const int col = bn + wc + nt * 16 + l15;
#pragma unroll
      for (int r = 0; r < 4; r++) {
        const int row = bm + wr + mt * 16 + quad * 4 + r;
        float v = acc[mt][nt][r];
        float other = __shfl_xor(v, 1, 64);
        const int pos = row & (S_ - 1);
        const int i   = (col & (HD_ - 1)) >> 1;
        const float c  = cosT[pos * (HD_ / 2) + i];
        const float sn = sinT[pos * (HD_ / 2) + i];
        const float vk = (lane & 1) ? (other * sn + v * c) : (v * c - other * sn);
        if (col < 1024) Kout[(size_t)row * 1024 + col]        = f32_bf16(vk);
        else            Vout[(size_t)row * 1024 + col - 1024] = f32_bf16(v);
      }
    }
  }
}

// 256x256-tile 8-phase/2-K-tile GEMM (unchanged from round 6/7).
template<bool ROPE, bool SCALE, bool OUTF32>
__global__ __launch_bounds__(512, 2)
void gemm256(const ushort16* __restrict__ A, const ushort16* __restrict__ B,
             void* __restrict__ Y, int N,
             const float* __restrict__ cosT, const float* __restrict__ sinT)
{
  constexpr int NT = H_ / 64;                      // 64 K-tiles
  __shared__ __align__(16) ushort16 LA[2][16384];  // [buf][256 rows x 64 k] bf16, 32KB
  __shared__ __align__(16) ushort16 LB[2][16384];

  const int bid = (int)blockIdx.x;
  const int wg  = (bid & 7) * ((int)gridDim.x >> 3) + (bid >> 3);
  const int nbx = N >> 8;
  const int bm = (wg / nbx) * 256, bn = (wg % nbx) * 256;

  const int tid = threadIdx.x, wave = tid >> 6, lane = tid & 63;
  const int l15 = lane & 15, quad = lane >> 4;
  const int wm = wave >> 2, wn = wave & 3;

  const int s1 = 512 + tid;
  const int off0 = (tid >> 3) * 4096 + (((tid & 7) ^ ((tid >> 3) & 7)) * 8);
  const int off1 = (s1  >> 3) * 4096 + (((s1  & 7) ^ ((s1  >> 3) & 7)) * 8);

  auto STG_A = [&](int kt, int h) {
    const ushort16* g = A + (size_t)(bm + h * 128) * 4096 + kt * 64;
    ushort16* d = &LA[kt & 1][h * 8192 + wave * 512];
    gld16(g + off0, d);
    gld16(g + off1, d + 4096);
  };
  auto STG_B = [&](int kt, int h) {
    const ushort16* g = B + (size_t)(bn + h * 128) * 4096 + kt * 64;
    ushort16* d = &LB[kt & 1][h * 8192 + wave * 512];
    gld16(g + off0, d);
    gld16(g + off1, d + 4096);
  };

  const int slotk0 = ((0 * 4 + quad) ^ (l15 & 7)) * 8;
  const int slotk1 = ((1 * 4 + quad) ^ (l15 & 7)) * 8;

  short8 fragA[4][2];
  short8 b10[2], b11[2];
  short8 b0a0[2], b0a1[2];
  short8 b0b0[2], b0b1[2];
  floatx4 acc[8][4] = {};

#define G256_LDA(CA_, jm0)                                                    \
  do {                                                                        \
    _Pragma("unroll") for (int j = 0; j < 4; j++) {                           \
      const int R = (2 * ((jm0) + j) + wm) * 16 + l15;                        \
      fragA[j][0] = *(const short8*)((CA_) + R * 64 + slotk0);                \
      fragA[j][1] = *(const short8*)((CA_) + R * 64 + slotk1);                \
    }                                                                         \
  } while (0)

#define G256_LDB(LB_, jn0, D0, D1)                                            \
  do {                                                                        \
    { const int R = (4 * (jn0) + wn) * 16 + l15;                              \
      D0[0] = *(const short8*)((LB_) + R * 64 + slotk0);                      \
      D0[1] = *(const short8*)((LB_) + R * 64 + slotk1); }                    \
    { const int R = (4 * ((jn0) + 1) + wn) * 16 + l15;                        \
      D1[0] = *(const short8*)((LB_) + R * 64 + slotk0);                      \
      D1[1] = *(const short8*)((LB_) + R * 64 + slotk1); }                    \
  } while (0)

#define G256_MM(jm0, jn0, B0, B1)                                             \
  do {                                                                        \
    __builtin_amdgcn_s_setprio(1);                                            \
    _Pragma("unroll") for (int j = 0; j < 4; j++) {                           \
      acc[(jm0) + j][(jn0)] =                                                 \
          __builtin_amdgcn_mfma_f32_16x16x32_bf16(fragA[j][0], B0[0], acc[(jm0) + j][(jn0)], 0, 0, 0); \
      acc[(jm0) + j][(jn0)] =                                                 \
          __builtin_amdgcn_mfma_f32_16x16x32_bf16(fragA[j][1], B0[1], acc[(jm0) + j][(jn0)], 0, 0, 0); \
      acc[(jm0) + j][(jn0) + 1] =                                             \
          __builtin_amdgcn_mfma_f32_16x16x32_bf16(fragA[j][0], B1[0], acc[(jm0) + j][(jn0) + 1], 0, 0, 0); \
      acc[(jm0) + j][(jn0) + 1] =                                             \
          __builtin_amdgcn_mfma_f32_16x16x32_bf16(fragA[j][1], B1[1], acc[(jm0) + j][(jn0) + 1], 0, 0, 0); \
    }                                                                         \
    __builtin_amdgcn_s_setprio(0);                                            \
  } while (0)

#define BARRIER __builtin_amdgcn_s_barrier()
#define LGK0 do { asm volatile("s_waitcnt lgkmcnt(0)" ::: "memory");          \
                  __builtin_amdgcn_sched_barrier(0); } while (0)
#define VMC(t) do {                                                           \
    if ((t) < NT - 2) asm volatile("s_waitcnt vmcnt(6)" ::: "memory");        \
    else              asm volatile("s_waitcnt vmcnt(0)" ::: "memory");        \
  } while (0)

#define G256_TILE(t, C0, C1, N0, N1)                                          \
  do {                                                                        \
    const ushort16* CA_ = &LA[(t) & 1][0];                                    \
    const ushort16* CB_ = &LB[(t) & 1][0];                                    \
    G256_LDA(CA_, 0);                                                         \
    if ((t) + 1 < NT) STG_A((t) + 1, 0);                                      \
    BARRIER; LGK0;                                                            \
    G256_MM(0, 0, C0, C1);                                                    \
    VMC(t); BARRIER;                                                          \
    G256_LDB(CB_, 2, b10, b11);                                               \
    if ((t) + 1 < NT) STG_B((t) + 1, 1);                                      \
    BARRIER; LGK0;                                                            \
    G256_MM(0, 2, b10, b11);                                                  \
    VMC(t); BARRIER;                                                          \
    G256_LDA(CA_, 4);                                                         \
    if ((t) + 1 < NT) STG_A((t) + 1, 1);                                      \
    BARRIER; LGK0;                                                            \
    G256_MM(4, 2, b10, b11);                                                  \
    VMC(t); BARRIER;                                                          \
    if ((t) + 1 < NT) G256_LDB(&LB[((t) + 1) & 1][0], 0, N0, N1);             \
    if ((t) + 2 < NT) STG_B((t) + 2, 0);                                      \
    BARRIER;                                                                  \
    G256_MM(4, 0, C0, C1);                                                    \
    VMC(t); BARRIER;                                                          \
  } while (0)

  STG_B(0, 0);
  STG_A(0, 0);
  asm volatile("s_waitcnt vmcnt(0)" ::: "memory");
  BARRIER;
  G256_LDB(&LB[0][0], 0, b0a0, b0a1);
  STG_B(0, 1);
  STG_A(0, 1);
  STG_B(1, 0);

#pragma unroll 1
  for (int t0 = 0; t0 < NT; t0 += 2) {
    G256_TILE(t0,     b0a0, b0a1, b0b0, b0b1);
    G256_TILE(t0 + 1, b0b0, b0b1, b0a0, b0a1);
  }

#undef G256_LDA
#undef G256_LDB
#undef G256_MM
#undef G256_TILE
#undef BARRIER
#undef LGK0
#undef VMC

#pragma unroll
  for (int jm = 0; jm < 8; jm++) {
#pragma unroll
    for (int jn = 0; jn < 4; jn++) {
      const int col = bn + (4 * jn + wn) * 16 + l15;
#pragma unroll
      for (int r = 0; r < 4; r++) {
        const int row = bm + (2 * jm + wm) * 16 + quad * 4 + r;
        float v = acc[jm][jn][r];
        if (ROPE) {
          float other = __shfl_xor(v, 1, 64);
          const int pos = row & (S_ - 1);
          const int i   = (col & (HD_ - 1)) >> 1;
          const float c  = cosT[pos * (HD_ / 2) + i];
          const float sn = sinT[pos * (HD_ / 2) + i];
          v = (lane & 1) ? (other * sn + v * c) : (v * c - other * sn);
        }
        if (SCALE) v *= (0.08838834764831845f * 1.4426950408889634f);
        if (OUTF32) ((float*)Y)[(size_t)row * N + col] = v;
        else        ((ushort16*)Y)[(size_t)row * N + col] = f32_bf16(v);
      }
    }
  }
}

// MFMA flash attention v6.
// grid (64, 8): x = (b,h) pair, y -> qb = 7-y (longest blocks stream first).
// 512 thr = 8 waves, 32 q-rows/wave (2 m-tiles), 256 rows/block.
// v6 vs v5: doubled rows/wave -> K-frags shared across both m-tiles in QK,
// V-frags shared in PV: 44 LDS-b128 ops per 64 MFMA (was 34 per 32) -- the
// K/V LDS reads (identical across all 8 waves) were the oversubscribed pipe.
// launch_bounds(512,2): 256-VGPR cap, body ~180 (v4's spill was the 128 cap).
// LDS 96KB -> 1 block/CU, 2 waves/SIMD (m214 8-warp QBLK=32 operating point).
__global__ __launch_bounds__(512, 2)
void flash_mfma(const ushort16* __restrict__ Qg, const ushort16* __restrict__ Kg,
                const ushort16* __restrict__ Vtg, ushort16* __restrict__ Cg)
{
  __shared__ __align__(16) ushort16 Ks[2][64 * 128];   // [key][dim], chunk-swizzled, 16 KB each
  __shared__ __align__(16) ushort16 VT[2][128 * 64];   // [dim][key], chunk-swizzled, 16 KB each
  __shared__ __align__(16) ushort16 Ps[8][32 * 64];    // per-wave P (2 m-tiles), 4 KB each

  const int tid = threadIdx.x, wave = tid >> 6, lane = tid & 63;
  const int l15 = lane & 15, quad = lane >> 4;
  const int bh = (int)blockIdx.x;
  const int qb = 7 - (int)blockIdx.y;                  // longest first (LPT stream)
  const int b = bh >> 5, h = bh & 31, kh = h >> 2;
  const int qrow0 = qb * 256 + wave * 32;

  // Q frags (B-operand; scale*log2e pre-folded): B[n=l15][k=quad*8+j]
  short8 aq[2][4];
  const ushort16* qbase = Qg + (size_t)(b * S_ + qrow0 + l15) * 4096 + h * 128 + quad * 8;
#pragma unroll
  for (int mt = 0; mt < 2; mt++)
#pragma unroll
    for (int ks = 0; ks < 4; ks++)
      aq[mt][ks] = *(const short8*)(qbase + mt * 16 * 4096 + ks * 32);

  // staging source offsets (XOR pre-swizzle on global source, linear LDS dest)
  int kOff[2], vOff[2];
#pragma unroll
  for (int it = 0; it < 2; it++) {
    const int s = it * 512 + tid;
    const int rK = s >> 4, cK = (s & 15) ^ (rK & 15);   // K tile: 64 rows x 16 chunks
    kOff[it] = rK * 1024 + cK * 8;
    const int dV = s >> 3, cV = (s & 7) ^ (dV & 7);     // VT tile: 128 rows x 8 chunks
    vOff[it] = dV * 4096 + cV * 8;
  }
  const ushort16* Kbase = Kg + (size_t)(b * S_) * 1024 + kh * 128;
  const ushort16* Vbase = Vtg + (size_t)(kh * 128) * 4096 + (size_t)b * S_;
  const int ktmax = 4 * qb + 3;

  auto STAGE = [&](int kt, int buf) {
    const ushort16* kg = Kbase + (size_t)kt * 65536;
    const ushort16* vg = Vbase + kt * 64;
#pragma unroll
    for (int it = 0; it < 2; it++) {
      gld16(kg + kOff[it], &Ks[buf][0] + it * 4096 + wave * 512);
      gld16(vg + vOff[it], &VT[buf][0] + it * 4096 + wave * 512);
    }
  };

  STAGE(0, 0);
  __syncthreads();   // drains vmcnt: buf0 ready

  floatx4 o0[8] = {}, o1[8] = {};
  float m0 = -1e30f, m1 = -1e30f, l0 = 0.f, l1 = 0.f;
  ushort16* Pw = &Ps[wave][0];

  for (int kt = 0; kt <= ktmax; ++kt) {
    const int cur = kt & 1;
    if (kt < ktmax) STAGE(kt + 1, cur ^ 1);   // issue next tile before compute
    const ushort16* KsC = &Ks[cur][0];
    const ushort16* VTC = &VT[cur][0];

    if (kt * 64 <= qrow0 + 31) {
      // S^T = K Q^T for both m-tiles; K-frags read once, used twice
      floatx4 s0[4] = {}, s1[4] = {};
      __builtin_amdgcn_s_setprio(1);
#pragma unroll
      for (int k4 = 0; k4 < 4; k4++)
#pragma unroll
        for (int ks = 0; ks < 4; ks++) {
          short8 ak = *(const short8*)(KsC + (k4 * 16 + l15) * 128 + (((ks * 4 + quad) ^ l15) * 8));
          s0[k4] = __builtin_amdgcn_mfma_f32_16x16x32_bf16(ak, aq[0][ks], s0[k4], 0, 0, 0);
          s1[k4] = __builtin_amdgcn_mfma_f32_16x16x32_bf16(ak, aq[1][ks], s1[k4], 0, 0, 0);
        }
      __builtin_amdgcn_s_setprio(0);

      // causal mask: q = qrow0 + mt*16 + l15, keys = kt*64 + k4*16 + quad*4 + r.
      // A fully-masked m-tile is safe: m_i already finite -> p = exp2(-huge) = 0.
      if (kt * 64 + 63 > qrow0) {
#pragma unroll
        for (int k4 = 0; k4 < 4; k4++) {
          const int key = kt * 64 + k4 * 16 + quad * 4;
#pragma unroll
          for (int r = 0; r < 4; r++) {
            if (key + r > qrow0 + l15)      s0[k4][r] = -1e30f;
            if (key + r > qrow0 + 16 + l15) s1[k4][r] = -1e30f;
          }
        }
      }

      // online softmax per m-tile (exp2 domain, defer-max THR=8)
#define FL_SOFTMAX(sv, m_i, l_i, ov, PBASE)                                   \
      {                                                                       \
        float mx = sv[0][0];                                                  \
        _Pragma("unroll") for (int k4 = 0; k4 < 4; k4++)                      \
          _Pragma("unroll") for (int r = 0; r < 4; r++)                       \
            mx = fmaxf(mx, sv[k4][r]);                                        \
        mx = fmaxf(mx, __shfl_xor(mx, 16, 64));                               \
        mx = fmaxf(mx, __shfl_xor(mx, 32, 64));                               \
        if (!__all(mx - m_i <= 8.f)) {                                        \
          const float mn = fmaxf(m_i, mx);                                    \
          const float alpha = exp2_fast(m_i - mn);                            \
          m_i = mn;                                                           \
          l_i *= alpha;                                                       \
          float ar[4];                                                        \
          _Pragma("unroll") for (int r = 0; r < 4; r++)                       \
            ar[r] = __shfl(alpha, quad * 4 + r, 64);                          \
          _Pragma("unroll") for (int dt = 0; dt < 8; dt++)                    \
            _Pragma("unroll") for (int r = 0; r < 4; r++)                     \
              ov[dt][r] *= ar[r];                                             \
        }                                                                     \
        const float m = m_i;                                                  \
        float rs = 0.f;                                                       \
        _Pragma("unroll") for (int k4 = 0; k4 < 4; k4++) {                    \
          const float p0 = exp2_fast(sv[k4][0] - m);                          \
          const float p1 = exp2_fast(sv[k4][1] - m);                          \
          const float p2 = exp2_fast(sv[k4][2] - m);                          \
          const float p3 = exp2_fast(sv[k4][3] - m);                          \
          rs += (p0 + p1) + (p2 + p3);                                        \
          uintx2 w;                                                           \
          w[0] = pk_bf16(p0, p1);                                             \
          w[1] = pk_bf16(p2, p3);                                             \
          *(uintx2*)(Pw + (PBASE) + l15 * 64 +                                \
                     (((k4 * 2 + (quad >> 1)) ^ (l15 & 7)) * 8) +             \
                     (quad & 1) * 4) = w;                                     \
        }                                                                     \
        rs += __shfl_xor(rs, 16, 64);                                         \
        rs += __shfl_xor(rs, 32, 64);                                         \
        l_i += rs;                                                            \
      }

      FL_SOFTMAX(s0, m0, l0, o0, 0)
      FL_SOFTMAX(s1, m1, l1, o1, 1024)
#undef FL_SOFTMAX

      // O += P V for both m-tiles; V-frags read once, used twice
      __builtin_amdgcn_s_setprio(1);
#pragma unroll
      for (int ks2 = 0; ks2 < 2; ks2++) {
        const int pswz = (((ks2 * 4 + quad) ^ (l15 & 7)) * 8);
        short8 ap0 = *(const short8*)(Pw + l15 * 64 + pswz);
        short8 ap1 = *(const short8*)(Pw + 1024 + l15 * 64 + pswz);
#pragma unroll
        for (int dt = 0; dt < 8; dt++) {
          short8 bv = *(const short8*)(VTC + (dt * 16 + l15) * 64 + pswz);
          o0[dt] = __builtin_amdgcn_mfma_f32_16x16x32_bf16(ap0, bv, o0[dt], 0, 0, 0);
          o1[dt] = __builtin_amdgcn_mfma_f32_16x16x32_bf16(ap1, bv, o1[dt], 0, 0, 0);
        }
      }
      __builtin_amdgcn_s_setprio(0);
    }
    __syncthreads();   // next buf staged; cur buf free to overwrite
  }

  // epilogue: rows qrow0 + mt*16 + quad*4 + r, cols h*128 + dt*16 + l15
  {
    const float li0 = 1.f / l0;
    float vr[4];
#pragma unroll
    for (int r = 0; r < 4; r++) vr[r] = __shfl(li0, quad * 4 + r, 64);
#pragma unroll
    for (int dt = 0; dt < 8; dt++)
#pragma unroll
      for (int r = 0; r < 4; r++)
        Cg[(size_t)(b * S_ + qrow0 + quad * 4 + r) * 4096 + h * 128 + dt * 16 + l15] =
            f32_bf16(o0[dt][r] * vr[r]);
  }
  {
    const float li1 = 1.f / l1;
    float vr[4];
#pragma unroll
    for (int r = 0; r < 4; r++) vr[r] = __shfl(li1, quad * 4 + r, 64);
#pragma unroll
    for (int dt = 0; dt < 8; dt++)
#pragma unroll
      for (int r = 0; r < 4; r++)
        Cg[(size_t)(b * S_ + qrow0 + 16 + quad * 4 + r) * 4096 + h * 128 + dt * 16 + l15] =
            f32_bf16(o1[dt][r] * vr[r]);
  }
}

extern "C" void kernel_launch(void* const* d_in, const int* in_sizes, int n_in,
                              void* d_out, int out_size, void* d_ws, size_t ws_size,
                              hipStream_t stream) {
  const float* hs   = (const float*)d_in[0];
  const float* cosT = (const float*)d_in[1];
  const float* sinT = (const float*)d_in[2];
  const float* Wq = (const float*)d_in[5];
  const float* Wk = (const float*)d_in[6];
  const float* Wv = (const float*)d_in[7];
  const float* Wo = (const float*)d_in[8];
  float* out = (float*)d_out;

  char* ws = (char*)d_ws;
  ushort16* hsB = (ushort16*)(ws);                      // 33.5 MB  (also reused as CB)
  ushort16* QB  = (ushort16*)(ws + 33554432);           // 33.5 MB
  ushort16* KB  = (ushort16*)(ws + 67108864);           // 8.4 MB
  ushort16* VB  = (ushort16*)(ws + 75497472);           // 8.4 MB
  ushort16* VTg = (ushort16*)(ws + 83886080);           // 8.4 MB
  ushort16* WB  = (ushort16*)(ws + 92274688);           // 33.5 MB (per-GEMM weight buf; KV: [Wk;Wv] stacked)
  ushort16* CB  = hsB;                                  // reuse hs region after KV GEMM

  dim3 blk(256);
  cvt_bf16<<<dim3(16384), blk, 0, stream>>>(hs, (uint32*)hsB);
  cvt_bf16<<<dim3(16384), blk, 0, stream>>>(Wq, (uint32*)WB);
  gemm256<true,  true,  false><<<dim3(256), dim3(512), 0, stream>>>(hsB, WB, QB, 4096, cosT, sinT);
  // fused K+V projection: WB = [Wk (rows 0-1023); Wv (rows 1024-2047)]
  cvt_bf16<<<dim3(4096),  blk, 0, stream>>>(Wk, (uint32*)WB);
  cvt_bf16<<<dim3(4096),  blk, 0, stream>>>(Wv, (uint32*)(WB + 4194304));
  gemm128_kv<<<dim3(16, 32), blk, 0, stream>>>(hsB, WB, KB, VB, cosT, sinT);
  transp<<<dim3(16, 64), blk, 0, stream>>>(VB, VTg);
  flash_mfma<<<dim3(64, 8), dim3(512), 0, stream>>>(QB, KB, VTg, CB);
  cvt_bf16<<<dim3(16384), blk, 0, stream>>>(Wo, (uint32*)WB);
  gemm256<false, false, true><<<dim3(256), dim3(512), 0, stream>>>(CB, WB, out, 4096, cosT, sinT);
}